// Round 1
// baseline (81.528 us; speedup 1.0000x reference)
//
#include <hip/hip_runtime.h>

// NF4 embedding dequant:
//   x:      [B,S] int32 token ids            (in_sizes[0] = B*S = 16384)
//   packed: [V, D/2] int32, one byte/elem    (in_sizes[1] = V*D/2)
//   lut:    [16] float32 NF4 codebook
//   c:      [1] float32, out = lut[nib] / c
// out: [B,S,D] float32, nibbles interleaved hi-first.

#define DPACK 2048          // D/2 packed elements per row
#define BLOCK 256

__global__ __launch_bounds__(BLOCK) void nf4_embed_kernel(
    const int* __restrict__ x,
    const int* __restrict__ packed,
    const float* __restrict__ lut,
    const float* __restrict__ c,
    float* __restrict__ out)
{
    __shared__ float slut[16];
    if (threadIdx.x < 16) {
        slut[threadIdx.x] = lut[threadIdx.x] / c[0];
    }
    __syncthreads();

    const int tok = blockIdx.x;
    const int row = x[tok];                       // block-uniform -> scalar load
    const int4* __restrict__ src =
        reinterpret_cast<const int4*>(packed + (size_t)row * DPACK);
    float4* __restrict__ dst =
        reinterpret_cast<float4*>(out + (size_t)tok * (2 * DPACK));

    const int t = threadIdx.x;
    // 512 int4 chunks per row; 256 threads -> 2 passes, fully coalesced.
    #pragma unroll
    for (int pass = 0; pass < 2; ++pass) {
        const int idx = t + pass * BLOCK;         // 0..511
        const int4 p = src[idx];
        float4 o0, o1;
        o0.x = slut[(p.x >> 4) & 15];
        o0.y = slut[ p.x       & 15];
        o0.z = slut[(p.y >> 4) & 15];
        o0.w = slut[ p.y       & 15];
        o1.x = slut[(p.z >> 4) & 15];
        o1.y = slut[ p.z       & 15];
        o1.z = slut[(p.w >> 4) & 15];
        o1.w = slut[ p.w       & 15];
        dst[idx * 2    ] = o0;
        dst[idx * 2 + 1] = o1;
    }
}

extern "C" void kernel_launch(void* const* d_in, const int* in_sizes, int n_in,
                              void* d_out, int out_size, void* d_ws, size_t ws_size,
                              hipStream_t stream) {
    const int*   x      = (const int*)d_in[0];
    const int*   packed = (const int*)d_in[1];
    const float* lut    = (const float*)d_in[2];
    const float* c      = (const float*)d_in[3];
    float*       out    = (float*)d_out;

    const int n_tok = in_sizes[0];                // B*S
    nf4_embed_kernel<<<n_tok, BLOCK, 0, stream>>>(x, packed, lut, c, out);
}

// Round 3
// 62.987 us; speedup vs baseline: 1.2944x; 1.2944x over previous
//
#include <hip/hip_runtime.h>

// NF4 embedding dequant:
//   x:      [B,S] int32 token ids            (in_sizes[0] = B*S = 16384)
//   packed: [V, D/2] int32, one byte/elem    (in_sizes[1] = V*D/2)
//   lut:    [16] float32 NF4 codebook
//   c:      [1] float32, out = lut[nib] / c
// out: [B,S,D] float32, nibbles interleaved hi-first.
//
// Layout: packed elem j of row -> out[2j] = lut[(p>>4)&15], out[2j+1] = lut[p&15].
// Each lane consumes an int2 (2 packed elems) -> exactly one float4 of output:
// both the 8 B/lane load and the 16 B/lane store are fully lane-contiguous.

#define DPACK 2048          // D/2 packed int32 per row
#define BLOCK 256
#define ITERS 4             // DPACK/2 int2-chunks (1024) / BLOCK

typedef float f32x4 __attribute__((ext_vector_type(4)));

__global__ __launch_bounds__(BLOCK) void nf4_embed_kernel(
    const int* __restrict__ x,
    const int* __restrict__ packed,
    const float* __restrict__ lut,
    const float* __restrict__ c,
    float* __restrict__ out)
{
    __shared__ float slut[16];
    if (threadIdx.x < 16) {
        slut[threadIdx.x] = lut[threadIdx.x] / c[0];
    }
    __syncthreads();

    const int tok = blockIdx.x;
    const int row = x[tok];                       // block-uniform -> scalar load
    const int2* __restrict__ src =
        reinterpret_cast<const int2*>(packed + (size_t)row * DPACK);
    f32x4* __restrict__ dst =
        reinterpret_cast<f32x4*>(out + (size_t)tok * (2 * DPACK));

    const int t = threadIdx.x;

    // Issue all loads first (4 independent dwordx2 in flight), then LUT+store.
    int2 p[ITERS];
    #pragma unroll
    for (int i = 0; i < ITERS; ++i)
        p[i] = src[t + i * BLOCK];

    #pragma unroll
    for (int i = 0; i < ITERS; ++i) {
        f32x4 o;
        o.x = slut[(p[i].x >> 4) & 15];
        o.y = slut[ p[i].x       & 15];
        o.z = slut[(p[i].y >> 4) & 15];
        o.w = slut[ p[i].y       & 15];
        __builtin_nontemporal_store(o, &dst[t + i * BLOCK]);
    }
}

extern "C" void kernel_launch(void* const* d_in, const int* in_sizes, int n_in,
                              void* d_out, int out_size, void* d_ws, size_t ws_size,
                              hipStream_t stream) {
    const int*   x      = (const int*)d_in[0];
    const int*   packed = (const int*)d_in[1];
    const float* lut    = (const float*)d_in[2];
    const float* c      = (const float*)d_in[3];
    float*       out    = (float*)d_out;

    const int n_tok = in_sizes[0];                // B*S
    nf4_embed_kernel<<<n_tok, BLOCK, 0, stream>>>(x, packed, lut, c, out);
}